// Round 7
// baseline (219.984 us; speedup 1.0000x reference)
//
#include <hip/hip_runtime.h>

typedef __attribute__((ext_vector_type(8))) __bf16 bf16x8;
typedef __attribute__((ext_vector_type(4))) __bf16 bf16x4;
typedef __attribute__((ext_vector_type(4))) float  f32x4;

static constexpr int TSEQ   = 2048;
static constexpr int DMODEL = 1024;
static constexpr int HD     = 64;
static constexpr int LSTR   = 72;   // LDS row stride (36 dwords): 8-phase-optimal b128 frags

// ---------------- convert x (fp32 -> bf16) ----------------
__global__ __launch_bounds__(256) void k_convert_x(const float* __restrict__ x,
                                                   __bf16* __restrict__ xbf) {
  size_t i = ((size_t)blockIdx.x * 256 + threadIdx.x) * 4;
  float4 v = *(const float4*)(x + i);
  bf16x4 o = { (__bf16)v.x, (__bf16)v.y, (__bf16)v.z, (__bf16)v.w };
  *(bf16x4*)(xbf + i) = o;
}

// ---------------- transpose + convert weights (fp32 [K][N] -> bf16 [N][K]) ----------------
__global__ __launch_bounds__(1024) void k_transpose_w(const float* __restrict__ w0,
    const float* __restrict__ w1, const float* __restrict__ w2,
    const float* __restrict__ w3, __bf16* __restrict__ wt_all) {
  __shared__ float tile[32][33];
  const float* w = blockIdx.z == 0 ? w0 : blockIdx.z == 1 ? w1 : blockIdx.z == 2 ? w2 : w3;
  __bf16* out = wt_all + (size_t)blockIdx.z * DMODEL * DMODEL;
  int n0 = blockIdx.x * 32, k0 = blockIdx.y * 32;
  int tx = threadIdx.x, ty = threadIdx.y;
  tile[ty][tx] = w[(size_t)(k0 + ty) * DMODEL + n0 + tx];
  __syncthreads();
  out[(size_t)(n0 + ty) * DMODEL + k0 + tx] = (__bf16)tile[tx][ty];
}

// ---------------- m97-style GEMM mainloop: global_load_lds width-16 staging ----------------
__device__ __forceinline__ void gemm_mainloop(const __bf16* __restrict__ A,
                                              const __bf16* __restrict__ Bt,
                                              int bm, int bn,
                                              __bf16* At, __bf16* Bl,
                                              f32x4 acc[4][4]) {
  const int tid  = threadIdx.x;
  const int lane = tid & 63;
  const int l15  = lane & 15, quad = lane >> 4;
  const int wv   = tid >> 6;
  const int wm   = (wv >> 1) * 64, wn = (wv & 1) * 64;
  const int s0   = wv * 2;
  const int srow = lane >> 2;
  const int scol = (lane & 3) << 3;
  for (int k0 = 0; k0 < 1024; k0 += 32) {
    __syncthreads();
#pragma unroll
    for (int ss = 0; ss < 2; ss++) {
      const int s   = s0 + ss;
      const int row = s * 16 + srow;
      const __bf16* ga = A  + (size_t)(bm + row) * 1024 + k0 + scol;
      const __bf16* gb = Bt + (size_t)(bn + row) * 1024 + k0 + scol;
      __builtin_amdgcn_global_load_lds(
          (const __attribute__((address_space(1))) void*)ga,
          (__attribute__((address_space(3))) void*)(At + s * 512), 16, 0, 0);
      __builtin_amdgcn_global_load_lds(
          (const __attribute__((address_space(1))) void*)gb,
          (__attribute__((address_space(3))) void*)(Bl + s * 512), 16, 0, 0);
    }
    __syncthreads();
    bf16x8 af[4], bfr[4];
#pragma unroll
    for (int mt = 0; mt < 4; mt++)
      af[mt] = *(const bf16x8*)(At + (wm + mt * 16 + l15) * 32 + quad * 8);
#pragma unroll
    for (int nt = 0; nt < 4; nt++)
      bfr[nt] = *(const bf16x8*)(Bl + (wn + nt * 16 + l15) * 32 + quad * 8);
#pragma unroll
    for (int mt = 0; mt < 4; mt++)
#pragma unroll
      for (int nt = 0; nt < 4; nt++)
        acc[mt][nt] = __builtin_amdgcn_mfma_f32_16x16x32_bf16(
            af[mt], bfr[nt], acc[mt][nt], 0, 0, 0);
  }
}

// ---------------- QKV projection (Q pre-scaled by 1/8; V row-major like K) ----------------
__global__ __launch_bounds__(256) void k_gemm_qkv(const __bf16* __restrict__ xbf,
    const __bf16* __restrict__ wt_all, __bf16* __restrict__ qws,
    __bf16* __restrict__ kws, __bf16* __restrict__ vws) {
  __shared__ __bf16 At[128 * 32];
  __shared__ __bf16 Bl[128 * 32];
  const int which = blockIdx.z;
  const __bf16* wt = wt_all + (size_t)which * DMODEL * DMODEL;
  const int bm = blockIdx.y * 128, bn = blockIdx.x * 128;
  f32x4 acc[4][4];
  const f32x4 z = {0.f, 0.f, 0.f, 0.f};
#pragma unroll
  for (int mt = 0; mt < 4; mt++)
#pragma unroll
    for (int nt = 0; nt < 4; nt++) acc[mt][nt] = z;
  gemm_mainloop(xbf, wt, bm, bn, At, Bl, acc);
  const int lane = threadIdx.x & 63;
  const int l15 = lane & 15, quad = lane >> 4;
  const int wv = threadIdx.x >> 6;
  const int wm = (wv >> 1) * 64, wn = (wv & 1) * 64;
#pragma unroll
  for (int mt = 0; mt < 4; mt++)
#pragma unroll
    for (int nt = 0; nt < 4; nt++)
#pragma unroll
      for (int r = 0; r < 4; r++) {
        int m = bm + wm + mt * 16 + quad * 4 + r;
        int n = bn + wn + nt * 16 + l15;
        int b = m >> 11, t = m & 2047;
        int h = n >> 6,  d = n & 63;
        int bh = b * 16 + h;
        float av = acc[mt][nt][r];
        if (which == 0)      qws[((size_t)bh * TSEQ + t) * HD + d] = (__bf16)(av * 0.125f);
        else if (which == 1) kws[((size_t)bh * TSEQ + t) * HD + d] = (__bf16)av;
        else                 vws[((size_t)bh * TSEQ + t) * HD + d] = (__bf16)av;
      }
}

// ---------------- flash attention: triple-buffered LDS, 2-deep prefetch ----------------
// Block = 64 q-rows, pair (qb0, 31-qb0) -> 33 tiles. lgkm-only barriers keep prefetch
// loads in flight. V transposed into LDS at staging (XOR swizzle t ^ 8*((d>>3)&7)).
__global__ __launch_bounds__(256) void k_attn(const __bf16* __restrict__ qws,
    const __bf16* __restrict__ kws, const __bf16* __restrict__ vws,
    __bf16* __restrict__ ctx) {
  const int qb0 = blockIdx.x, qb1 = 31 - qb0;
  const int bh  = blockIdx.y;
  const int tid = threadIdx.x;
  const int lane = tid & 63, wv = tid >> 6;
  const int l15 = lane & 15, quad = lane >> 4;
  const __bf16* qp = qws + (size_t)bh * TSEQ * HD;
  const __bf16* kp = kws + (size_t)bh * TSEQ * HD;
  const __bf16* vp = vws + (size_t)bh * TSEQ * HD;
  const int b = bh >> 4, h = bh & 15;

  __shared__ __bf16 kbuf[3][64 * LSTR];
  __shared__ __bf16 vbuf[3][64 * LSTR];   // [d][t ^ swz(d)]
  __shared__ __bf16 plds[4][16 * LSTR];

  const f32x4 z = {0.f, 0.f, 0.f, 0.f};
  const int sr = tid >> 3;        // 0..31
  const int sc = (tid & 7) * 8;   // 0..56

  const int qr0a = qb0 * 64 + wv * 16;
  const int qr0b = qb1 * 64 + wv * 16;
  bf16x8 aq0[2], aq1[2];
#pragma unroll
  for (int kb = 0; kb < 2; kb++) {
    aq0[kb] = *(const bf16x8*)(qp + (size_t)(qr0a + l15) * HD + kb * 32 + quad * 8);
    aq1[kb] = *(const bf16x8*)(qp + (size_t)(qr0b + l15) * HD + kb * 32 + quad * 8);
  }

  float lpart[4] = {0.f, 0.f, 0.f, 0.f};
  f32x4 acc[4];
#pragma unroll
  for (int dt = 0; dt < 4; dt++) acc[dt] = z;

  bf16x8 kA0, kA1, vA0, vA1;   // even tiles
  bf16x8 kB0, kB1, vB0, vB1;   // odd tiles

  auto load_tile = [&](int g, bf16x8& k0, bf16x8& k1, bf16x8& v0, bf16x8& v1) {
    const int kt = (g <= qb0 ? g : g - qb0 - 1) * 64;
    k0 = *(const bf16x8*)(kp + (size_t)(kt + sr) * HD + sc);
    k1 = *(const bf16x8*)(kp + (size_t)(kt + sr + 32) * HD + sc);
    v0 = *(const bf16x8*)(vp + (size_t)(kt + sr) * HD + sc);
    v1 = *(const bf16x8*)(vp + (size_t)(kt + sr + 32) * HD + sc);
  };
  auto store_tile = [&](int buf, const bf16x8& k0, const bf16x8& k1,
                        const bf16x8& v0, const bf16x8& v1) {
    *(bf16x8*)(kbuf[buf] + sr * LSTR + sc)        = k0;
    *(bf16x8*)(kbuf[buf] + (sr + 32) * LSTR + sc) = k1;
    const int t0 = sr ^ sc, t1 = (sr + 32) ^ sc;   // swz(d)=sc for d in [sc,sc+7]
#pragma unroll
    for (int j = 0; j < 8; j++) {
      vbuf[buf][(sc + j) * LSTR + t0] = v0[j];
      vbuf[buf][(sc + j) * LSTR + t1] = v1[j];
    }
  };
  auto lgkm_barrier = []() {
    asm volatile("s_waitcnt lgkmcnt(0)\n\ts_barrier" ::: "memory");
  };

  auto compute_tile = [&](int s) {
    const int cu = s % 3;
    const __bf16* kb_ = kbuf[cu];
    const __bf16* vb_ = vbuf[cu];
    const bool h0 = (s <= qb0);
    const bool masked = (s == qb0) || (s == 32);
    f32x4 sarr[4];
#pragma unroll
    for (int nt = 0; nt < 4; nt++) sarr[nt] = z;
#pragma unroll
    for (int nt = 0; nt < 4; nt++)
#pragma unroll
      for (int kb = 0; kb < 2; kb++) {
        bf16x8 bk = *(const bf16x8*)(kb_ + (nt * 16 + l15) * LSTR + kb * 32 + quad * 8);
        sarr[nt] = __builtin_amdgcn_mfma_f32_16x16x32_bf16(
            h0 ? aq0[kb] : aq1[kb], bk, sarr[nt], 0, 0, 0);
      }
    if (masked) {
#pragma unroll
      for (int r = 0; r < 4; r++) {
        const int qloc = wv * 16 + quad * 4 + r;
#pragma unroll
        for (int nt = 0; nt < 4; nt++) {
          int kloc = nt * 16 + l15;
          float p = (kloc <= qloc) ? __expf(sarr[nt][r]) : 0.f;
          lpart[r] += p;
          plds[wv][(quad * 4 + r) * LSTR + nt * 16 + l15] = (__bf16)p;
        }
      }
    } else {
#pragma unroll
      for (int r = 0; r < 4; r++)
#pragma unroll
        for (int nt = 0; nt < 4; nt++) {
          float p = __expf(sarr[nt][r]);
          lpart[r] += p;
          plds[wv][(quad * 4 + r) * LSTR + nt * 16 + l15] = (__bf16)p;
        }
    }
#pragma unroll
    for (int kb = 0; kb < 2; kb++) {
      bf16x8 ap = *(const bf16x8*)(&plds[wv][l15 * LSTR + kb * 32 + quad * 8]);
#pragma unroll
      for (int dt = 0; dt < 4; dt++) {
        const int d = dt * 16 + l15;
        const int e = ((dt * 2 + (l15 >> 3)) & 7) * 8;
        bf16x8 bvv = *(const bf16x8*)(vb_ + d * LSTR + ((kb * 32 + quad * 8) ^ e));
        acc[dt] = __builtin_amdgcn_mfma_f32_16x16x32_bf16(ap, bvv, acc[dt], 0, 0, 0);
      }
    }
  };

  auto finalize = [&](int s) {
    if ((s == qb0) || (s == 32)) {
      const int qr0 = (s == 32) ? qr0b : qr0a;
#pragma unroll
      for (int r = 0; r < 4; r++) {
        float l = lpart[r];
        l += __shfl_xor(l, 1, 64);
        l += __shfl_xor(l, 2, 64);
        l += __shfl_xor(l, 4, 64);
        l += __shfl_xor(l, 8, 64);
        float linv = 1.f / l;
        const int qrow = qr0 + quad * 4 + r;
#pragma unroll
        for (int dt = 0; dt < 4; dt++)
          ctx[((size_t)(b * TSEQ + qrow)) * DMODEL + h * 64 + dt * 16 + l15] =
              (__bf16)(acc[dt][r] * linv);
        lpart[r] = 0.f;
      }
#pragma unroll
      for (int dt = 0; dt < 4; dt++) acc[dt] = z;
    }
  };

  // prologue: tile0 staged; tiles 1,2 in flight (2-deep)
  load_tile(0, kA0, kA1, vA0, vA1);
  store_tile(0, kA0, kA1, vA0, vA1);
  load_tile(1, kB0, kB1, vB0, vB1);
  load_tile(2, kA0, kA1, vA0, vA1);
  lgkm_barrier();

  for (int sb = 0; sb < 34; sb += 2) {
    {
      const int s = sb;                 // even: odd tiles live in set B
      compute_tile(s);
      if (s + 1 < 33) store_tile((s + 1) % 3, kB0, kB1, vB0, vB1);
      if (s + 3 < 33) load_tile(s + 3, kB0, kB1, vB0, vB1);
      finalize(s);
      lgkm_barrier();
    }
    if (sb + 1 < 33) {
      const int s = sb + 1;             // odd: even tiles live in set A
      compute_tile(s);
      if (s + 1 < 33) store_tile((s + 1) % 3, kA0, kA1, vA0, vA1);
      if (s + 3 < 33) load_tile(s + 3, kA0, kA1, vA0, vA1);
      finalize(s);
      lgkm_barrier();
    }
  }
}

// ---------------- output projection + bias (fp32 out) ----------------
__global__ __launch_bounds__(256) void k_gemm_out(const __bf16* __restrict__ ctx,
    const __bf16* __restrict__ wot, const float* __restrict__ bo,
    float* __restrict__ out) {
  __shared__ __bf16 At[128 * 32];
  __shared__ __bf16 Bl[128 * 32];
  const int bm = blockIdx.y * 128, bn = blockIdx.x * 128;
  f32x4 acc[4][4];
  const f32x4 z = {0.f, 0.f, 0.f, 0.f};
#pragma unroll
  for (int mt = 0; mt < 4; mt++)
#pragma unroll
    for (int nt = 0; nt < 4; nt++) acc[mt][nt] = z;
  gemm_mainloop(ctx, wot, bm, bn, At, Bl, acc);
  const int lane = threadIdx.x & 63;
  const int l15 = lane & 15, quad = lane >> 4;
  const int wv = threadIdx.x >> 6;
  const int wm = (wv >> 1) * 64, wn = (wv & 1) * 64;
#pragma unroll
  for (int mt = 0; mt < 4; mt++)
#pragma unroll
    for (int nt = 0; nt < 4; nt++)
#pragma unroll
      for (int r = 0; r < 4; r++) {
        int m = bm + wm + mt * 16 + quad * 4 + r;
        int n = bn + wn + nt * 16 + l15;
        out[(size_t)m * DMODEL + n] = acc[mt][nt][r] + bo[n];
      }
}

extern "C" void kernel_launch(void* const* d_in, const int* in_sizes, int n_in,
                              void* d_out, int out_size, void* d_ws, size_t ws_size,
                              hipStream_t stream) {
  const float* x  = (const float*)d_in[0];
  const float* Wq = (const float*)d_in[1];
  const float* Wk = (const float*)d_in[2];
  const float* Wv = (const float*)d_in[3];
  const float* Wo = (const float*)d_in[4];
  const float* bo = (const float*)d_in[5];
  float* out = (float*)d_out;

  __bf16* xbf = (__bf16*)d_ws;                        // 4096*1024
  __bf16* wt  = xbf + (size_t)4096 * 1024;            // 4 * 1024*1024
  __bf16* qws = wt  + (size_t)4 * 1024 * 1024;        // [32][2048][64]
  __bf16* kws = qws + (size_t)32 * 2048 * 64;
  __bf16* vws = kws + (size_t)32 * 2048 * 64;         // [32][2048][64]
  __bf16* ctx = xbf;                                  // aliases xbf (dead after QKV)

  k_convert_x<<<4096, 256, 0, stream>>>(x, xbf);
  k_transpose_w<<<dim3(32, 32, 4), dim3(32, 32), 0, stream>>>(Wq, Wk, Wv, Wo, wt);
  k_gemm_qkv<<<dim3(8, 32, 3), 256, 0, stream>>>(xbf, wt, qws, kws, vws);
  k_attn<<<dim3(16, 32), 256, 0, stream>>>(qws, kws, vws, ctx);
  k_gemm_out<<<dim3(8, 32), 256, 0, stream>>>(ctx, wt + (size_t)3 * 1024 * 1024, bo, out);
}

// Round 8
// 218.703 us; speedup vs baseline: 1.0059x; 1.0059x over previous
//
#include <hip/hip_runtime.h>

typedef __attribute__((ext_vector_type(8))) __bf16 bf16x8;
typedef __attribute__((ext_vector_type(4))) __bf16 bf16x4;
typedef __attribute__((ext_vector_type(4))) float  f32x4;

static constexpr int TSEQ    = 2048;
static constexpr int DMODEL  = 1024;
static constexpr int HD      = 64;
static constexpr int VSTRIDE = 2080;   // V^T row stride (breaks 4KB L2-channel aliasing)
static constexpr int LSTR    = 72;     // attn LDS row stride (36 dwords)

#define AS1 __attribute__((address_space(1)))
#define AS3 __attribute__((address_space(3)))

// ---------------- convert x (fp32 -> bf16) ----------------
__global__ __launch_bounds__(256) void k_convert_x(const float* __restrict__ x,
                                                   __bf16* __restrict__ xbf) {
  size_t i = ((size_t)blockIdx.x * 256 + threadIdx.x) * 4;
  float4 v = *(const float4*)(x + i);
  bf16x4 o = { (__bf16)v.x, (__bf16)v.y, (__bf16)v.z, (__bf16)v.w };
  *(bf16x4*)(xbf + i) = o;
}

// ---------------- transpose + convert weights (fp32 [K][N] -> bf16 [N][K]) ----------------
__global__ __launch_bounds__(1024) void k_transpose_w(const float* __restrict__ w0,
    const float* __restrict__ w1, const float* __restrict__ w2,
    const float* __restrict__ w3, __bf16* __restrict__ wt_all) {
  __shared__ float tile[32][33];
  const float* w = blockIdx.z == 0 ? w0 : blockIdx.z == 1 ? w1 : blockIdx.z == 2 ? w2 : w3;
  __bf16* out = wt_all + (size_t)blockIdx.z * DMODEL * DMODEL;
  int n0 = blockIdx.x * 32, k0 = blockIdx.y * 32;
  int tx = threadIdx.x, ty = threadIdx.y;
  tile[ty][tx] = w[(size_t)(k0 + ty) * DMODEL + n0 + tx];
  __syncthreads();
  out[(size_t)(n0 + ty) * DMODEL + k0 + tx] = (__bf16)tile[tx][ty];
}

// ---------------- BK=64 mainloop: two m97-layout sub-tiles, 32 MFMA per barrier ----------------
// At/Bl each hold TWO 128x32 unpadded sub-tiles (kb*4096 elements apart), staged by
// global_load_lds width=16. Halves the vmcnt(0)+barrier drains vs BK=32.
__device__ __forceinline__ void gemm_mainloop(const __bf16* __restrict__ A,
                                              const __bf16* __restrict__ Bt,
                                              int bm, int bn,
                                              __bf16* At, __bf16* Bl,
                                              f32x4 acc[4][4]) {
  const int tid  = threadIdx.x;
  const int lane = tid & 63;
  const int l15  = lane & 15, quad = lane >> 4;
  const int wv   = tid >> 6;
  const int wm   = (wv >> 1) * 64, wn = (wv & 1) * 64;
  const int s0   = wv * 2;
  const int srow = lane >> 2;
  const int scol = (lane & 3) << 3;
  for (int k0 = 0; k0 < 1024; k0 += 64) {
    __syncthreads();
#pragma unroll
    for (int ss = 0; ss < 2; ss++) {
      const int s   = s0 + ss;
      const int row = s * 16 + srow;
      const __bf16* ga = A  + (size_t)(bm + row) * 1024 + k0 + scol;
      const __bf16* gb = Bt + (size_t)(bn + row) * 1024 + k0 + scol;
#pragma unroll
      for (int kb = 0; kb < 2; kb++) {
        __builtin_amdgcn_global_load_lds((const AS1 void*)(ga + kb * 32),
                                         (AS3 void*)(At + kb * 4096 + s * 512), 16, 0, 0);
        __builtin_amdgcn_global_load_lds((const AS1 void*)(gb + kb * 32),
                                         (AS3 void*)(Bl + kb * 4096 + s * 512), 16, 0, 0);
      }
    }
    __syncthreads();
#pragma unroll
    for (int kb = 0; kb < 2; kb++) {
      bf16x8 af[4], bfr[4];
#pragma unroll
      for (int mt = 0; mt < 4; mt++)
        af[mt] = *(const bf16x8*)(At + kb * 4096 + (wm + mt * 16 + l15) * 32 + quad * 8);
#pragma unroll
      for (int nt = 0; nt < 4; nt++)
        bfr[nt] = *(const bf16x8*)(Bl + kb * 4096 + (wn + nt * 16 + l15) * 32 + quad * 8);
#pragma unroll
      for (int mt = 0; mt < 4; mt++)
#pragma unroll
        for (int nt = 0; nt < 4; nt++)
          acc[mt][nt] = __builtin_amdgcn_mfma_f32_16x16x32_bf16(
              af[mt], bfr[nt], acc[mt][nt], 0, 0, 0);
    }
  }
}

// ---------------- QKV projection (Q pre-scaled by 1/8; V stored transposed) ----------------
__global__ __launch_bounds__(256) void k_gemm_qkv(const __bf16* __restrict__ xbf,
    const __bf16* __restrict__ wt_all, __bf16* __restrict__ qws,
    __bf16* __restrict__ kws, __bf16* __restrict__ vtws) {
  __shared__ __bf16 At[2 * 128 * 32];
  __shared__ __bf16 Bl[2 * 128 * 32];
  const int which = blockIdx.z;
  const __bf16* wt = wt_all + (size_t)which * DMODEL * DMODEL;
  const int bm = blockIdx.y * 128, bn = blockIdx.x * 128;
  f32x4 acc[4][4];
  const f32x4 z = {0.f, 0.f, 0.f, 0.f};
#pragma unroll
  for (int mt = 0; mt < 4; mt++)
#pragma unroll
    for (int nt = 0; nt < 4; nt++) acc[mt][nt] = z;
  gemm_mainloop(xbf, wt, bm, bn, At, Bl, acc);
  const int lane = threadIdx.x & 63;
  const int l15 = lane & 15, quad = lane >> 4;
  const int wv = threadIdx.x >> 6;
  const int wm = (wv >> 1) * 64, wn = (wv & 1) * 64;
#pragma unroll
  for (int mt = 0; mt < 4; mt++)
#pragma unroll
    for (int nt = 0; nt < 4; nt++)
#pragma unroll
      for (int r = 0; r < 4; r++) {
        int m = bm + wm + mt * 16 + quad * 4 + r;
        int n = bn + wn + nt * 16 + l15;
        int b = m >> 11, t = m & 2047;
        int h = n >> 6,  d = n & 63;
        int bh = b * 16 + h;
        float av = acc[mt][nt][r];
        if (which == 0)      qws[((size_t)bh * TSEQ + t) * HD + d] = (__bf16)(av * 0.125f);
        else if (which == 1) kws[((size_t)bh * TSEQ + t) * HD + d] = (__bf16)av;
        else                 vtws[((size_t)bh * HD + d) * VSTRIDE + t] = (__bf16)av;
      }
}

// ---------------- flash attention: R6 structure (double-buffered LDS K/V) ----------------
__global__ __launch_bounds__(256) void k_attn(const __bf16* __restrict__ qws,
    const __bf16* __restrict__ kws, const __bf16* __restrict__ vtws,
    __bf16* __restrict__ ctx) {
  const int qb0 = blockIdx.x, qb1 = 31 - qb0;
  const int bh  = blockIdx.y;
  const int tid = threadIdx.x;
  const int lane = tid & 63, wv = tid >> 6;
  const int l15 = lane & 15, quad = lane >> 4;
  const __bf16* qp = qws  + (size_t)bh * TSEQ * HD;
  const __bf16* kp = kws  + (size_t)bh * TSEQ * HD;
  const __bf16* vp = vtws + (size_t)bh * HD * VSTRIDE;
  const int b = bh >> 4, h = bh & 15;

  __shared__ __bf16 kbuf[2][64 * LSTR];
  __shared__ __bf16 vbuf[2][64 * LSTR];
  __shared__ __bf16 plds[4][16 * LSTR];   // stride 72: 8-phase reads, conflict-free writes

  const f32x4 z = {0.f, 0.f, 0.f, 0.f};
  const int sr = tid >> 3, sc = (tid & 7) * 8;

  const int qr0a = qb0 * 64 + wv * 16;
  const int qr0b = qb1 * 64 + wv * 16;
  bf16x8 aq0[2], aq1[2];
#pragma unroll
  for (int kb = 0; kb < 2; kb++) {
    aq0[kb] = *(const bf16x8*)(qp + (size_t)(qr0a + l15) * HD + kb * 32 + quad * 8);
    aq1[kb] = *(const bf16x8*)(qp + (size_t)(qr0b + l15) * HD + kb * 32 + quad * 8);
  }

  bf16x8 kreg[2], vreg[2];
  kreg[0] = *(const bf16x8*)(kp + (size_t)sr * HD + sc);
  kreg[1] = *(const bf16x8*)(kp + (size_t)(sr + 32) * HD + sc);
  vreg[0] = *(const bf16x8*)(vp + (size_t)sr * VSTRIDE + sc);
  vreg[1] = *(const bf16x8*)(vp + (size_t)(sr + 32) * VSTRIDE + sc);
  *(bf16x8*)(kbuf[0] + sr * LSTR + sc)        = kreg[0];
  *(bf16x8*)(kbuf[0] + (sr + 32) * LSTR + sc) = kreg[1];
  *(bf16x8*)(vbuf[0] + sr * LSTR + sc)        = vreg[0];
  *(bf16x8*)(vbuf[0] + (sr + 32) * LSTR + sc) = vreg[1];
  __syncthreads();

  float lpart[4] = {0.f, 0.f, 0.f, 0.f};
  f32x4 acc[4];
#pragma unroll
  for (int dt = 0; dt < 4; dt++) acc[dt] = z;

  for (int s = 0; s < 33; s++) {
    const int cur = s & 1;
    const bool h0 = (s <= qb0);
    const bool masked = (s == qb0) || (s == 32);

    if (s + 1 < 33) {
      const int ktn = (s + 1 <= qb0) ? (s + 1) * 64 : (s - qb0) * 64;
      kreg[0] = *(const bf16x8*)(kp + (size_t)(ktn + sr) * HD + sc);
      kreg[1] = *(const bf16x8*)(kp + (size_t)(ktn + sr + 32) * HD + sc);
      vreg[0] = *(const bf16x8*)(vp + (size_t)sr * VSTRIDE + ktn + sc);
      vreg[1] = *(const bf16x8*)(vp + (size_t)(sr + 32) * VSTRIDE + ktn + sc);
    }

    const __bf16* kb_ = kbuf[cur];
    const __bf16* vb_ = vbuf[cur];
    f32x4 sarr[4];
#pragma unroll
    for (int nt = 0; nt < 4; nt++) sarr[nt] = z;
#pragma unroll
    for (int nt = 0; nt < 4; nt++)
#pragma unroll
      for (int kb = 0; kb < 2; kb++) {
        bf16x8 bk = *(const bf16x8*)(kb_ + (nt * 16 + l15) * LSTR + kb * 32 + quad * 8);
        bf16x8 a  = h0 ? aq0[kb] : aq1[kb];
        sarr[nt] = __builtin_amdgcn_mfma_f32_16x16x32_bf16(a, bk, sarr[nt], 0, 0, 0);
      }
    if (masked) {
#pragma unroll
      for (int r = 0; r < 4; r++) {
        const int qloc = wv * 16 + quad * 4 + r;
#pragma unroll
        for (int nt = 0; nt < 4; nt++) {
          int kloc = nt * 16 + l15;
          float p = (kloc <= qloc) ? __expf(sarr[nt][r]) : 0.f;
          lpart[r] += p;
          plds[wv][(quad * 4 + r) * LSTR + nt * 16 + l15] = (__bf16)p;
        }
      }
    } else {
#pragma unroll
      for (int r = 0; r < 4; r++)
#pragma unroll
        for (int nt = 0; nt < 4; nt++) {
          float p = __expf(sarr[nt][r]);
          lpart[r] += p;
          plds[wv][(quad * 4 + r) * LSTR + nt * 16 + l15] = (__bf16)p;
        }
    }
#pragma unroll
    for (int kb = 0; kb < 2; kb++) {
      bf16x8 ap = *(const bf16x8*)(&plds[wv][l15 * LSTR + kb * 32 + quad * 8]);
#pragma unroll
      for (int dt = 0; dt < 4; dt++) {
        bf16x8 bvv = *(const bf16x8*)(vb_ + (dt * 16 + l15) * LSTR + kb * 32 + quad * 8);
        acc[dt] = __builtin_amdgcn_mfma_f32_16x16x32_bf16(ap, bvv, acc[dt], 0, 0, 0);
      }
    }

    if (s + 1 < 33) {
      const int nxt = cur ^ 1;
      *(bf16x8*)(kbuf[nxt] + sr * LSTR + sc)        = kreg[0];
      *(bf16x8*)(kbuf[nxt] + (sr + 32) * LSTR + sc) = kreg[1];
      *(bf16x8*)(vbuf[nxt] + sr * LSTR + sc)        = vreg[0];
      *(bf16x8*)(vbuf[nxt] + (sr + 32) * LSTR + sc) = vreg[1];
    }
    __syncthreads();

    if (masked) {
      const int qr0 = h0 ? qr0a : qr0b;
#pragma unroll
      for (int r = 0; r < 4; r++) {
        float l = lpart[r];
        l += __shfl_xor(l, 1, 64);
        l += __shfl_xor(l, 2, 64);
        l += __shfl_xor(l, 4, 64);
        l += __shfl_xor(l, 8, 64);
        float linv = 1.f / l;
        const int qrow = qr0 + quad * 4 + r;
#pragma unroll
        for (int dt = 0; dt < 4; dt++)
          ctx[((size_t)(b * TSEQ + qrow)) * DMODEL + h * 64 + dt * 16 + l15] =
              (__bf16)(acc[dt][r] * linv);
        lpart[r] = 0.f;
      }
#pragma unroll
      for (int dt = 0; dt < 4; dt++) acc[dt] = z;
    }
  }
}

// ---------------- output projection + bias (fp32 out) ----------------
__global__ __launch_bounds__(256) void k_gemm_out(const __bf16* __restrict__ ctx,
    const __bf16* __restrict__ wot, const float* __restrict__ bo,
    float* __restrict__ out) {
  __shared__ __bf16 At[2 * 128 * 32];
  __shared__ __bf16 Bl[2 * 128 * 32];
  const int bm = blockIdx.y * 128, bn = blockIdx.x * 128;
  f32x4 acc[4][4];
  const f32x4 z = {0.f, 0.f, 0.f, 0.f};
#pragma unroll
  for (int mt = 0; mt < 4; mt++)
#pragma unroll
    for (int nt = 0; nt < 4; nt++) acc[mt][nt] = z;
  gemm_mainloop(ctx, wot, bm, bn, At, Bl, acc);
  const int lane = threadIdx.x & 63;
  const int l15 = lane & 15, quad = lane >> 4;
  const int wv = threadIdx.x >> 6;
  const int wm = (wv >> 1) * 64, wn = (wv & 1) * 64;
#pragma unroll
  for (int mt = 0; mt < 4; mt++)
#pragma unroll
    for (int nt = 0; nt < 4; nt++)
#pragma unroll
      for (int r = 0; r < 4; r++) {
        int m = bm + wm + mt * 16 + quad * 4 + r;
        int n = bn + wn + nt * 16 + l15;
        out[(size_t)m * DMODEL + n] = acc[mt][nt][r] + bo[n];
      }
}

extern "C" void kernel_launch(void* const* d_in, const int* in_sizes, int n_in,
                              void* d_out, int out_size, void* d_ws, size_t ws_size,
                              hipStream_t stream) {
  const float* x  = (const float*)d_in[0];
  const float* Wq = (const float*)d_in[1];
  const float* Wk = (const float*)d_in[2];
  const float* Wv = (const float*)d_in[3];
  const float* Wo = (const float*)d_in[4];
  const float* bo = (const float*)d_in[5];
  float* out = (float*)d_out;

  __bf16* xbf  = (__bf16*)d_ws;                       // 4096*1024
  __bf16* wt   = xbf  + (size_t)4096 * 1024;          // 4 * 1024*1024
  __bf16* qws  = wt   + (size_t)4 * 1024 * 1024;      // [32][2048][64]
  __bf16* kws  = qws  + (size_t)32 * 2048 * 64;
  __bf16* vtws = kws  + (size_t)32 * 2048 * 64;       // [32][64][VSTRIDE]
  __bf16* ctx  = xbf;                                 // aliases xbf (dead after QKV)

  k_convert_x<<<4096, 256, 0, stream>>>(x, xbf);
  k_transpose_w<<<dim3(32, 32, 4), dim3(32, 32), 0, stream>>>(Wq, Wk, Wv, Wo, wt);
  k_gemm_qkv<<<dim3(8, 32, 3), 256, 0, stream>>>(xbf, wt, qws, kws, vtws);
  k_attn<<<dim3(16, 32), 256, 0, stream>>>(qws, kws, vtws, ctx);
  k_gemm_out<<<dim3(8, 32), 256, 0, stream>>>(ctx, wt + (size_t)3 * 1024 * 1024, bo, out);
}

// Round 9
// 190.910 us; speedup vs baseline: 1.1523x; 1.1456x over previous
//
#include <hip/hip_runtime.h>

typedef __attribute__((ext_vector_type(8))) __bf16 bf16x8;
typedef __attribute__((ext_vector_type(4))) __bf16 bf16x4;
typedef __attribute__((ext_vector_type(4))) float  f32x4;

static constexpr int TSEQ    = 2048;
static constexpr int DMODEL  = 1024;
static constexpr int HD      = 64;
static constexpr int VSTRIDE = 2080;   // V^T row stride (breaks 4KB L2-channel aliasing)
static constexpr int LSTR    = 72;     // attn LDS row stride (36 dwords, 8-phase b128)

#define AS1 __attribute__((address_space(1)))
#define AS3 __attribute__((address_space(3)))

// ---------------- fused preprocessing: convert x + transpose weights ----------------
// blocks [0,4096): x fp32->bf16 (1024 elems each). blocks [4096,8192): one 32x32
// weight transpose tile each (fp32 [K][N] -> bf16 [N][K]).
__global__ __launch_bounds__(256) void k_prep(const float* __restrict__ x,
    const float* __restrict__ w0, const float* __restrict__ w1,
    const float* __restrict__ w2, const float* __restrict__ w3,
    __bf16* __restrict__ xbf, __bf16* __restrict__ wt_all) {
  __shared__ float tile[32][33];
  const int blk = blockIdx.x;
  const int tid = threadIdx.x;
  if (blk < 4096) {
    size_t i = ((size_t)blk * 256 + tid) * 4;
    float4 v = *(const float4*)(x + i);
    bf16x4 o = { (__bf16)v.x, (__bf16)v.y, (__bf16)v.z, (__bf16)v.w };
    *(bf16x4*)(xbf + i) = o;
    return;
  }
  const int tz = blk - 4096;
  const int wi = tz >> 10;                 // which weight
  const int tl = tz & 1023;
  const int n0 = (tl & 31) * 32, k0 = (tl >> 5) * 32;
  const float* w = wi == 0 ? w0 : wi == 1 ? w1 : wi == 2 ? w2 : w3;
  __bf16* out = wt_all + (size_t)wi * DMODEL * DMODEL;
  const int tx = tid & 31, ty0 = (tid >> 5) * 4;
#pragma unroll
  for (int j = 0; j < 4; j++)
    tile[ty0 + j][tx] = w[(size_t)(k0 + ty0 + j) * DMODEL + n0 + tx];
  __syncthreads();
#pragma unroll
  for (int j = 0; j < 4; j++)
    out[(size_t)(n0 + ty0 + j) * DMODEL + k0 + tx] = (__bf16)tile[tx][ty0 + j];
}

// ---------------- m97-style GEMM mainloop (R6): global_load_lds width-16, BK=32 ----------------
__device__ __forceinline__ void gemm_mainloop(const __bf16* __restrict__ A,
                                              const __bf16* __restrict__ Bt,
                                              int bm, int bn,
                                              __bf16* At, __bf16* Bl,
                                              f32x4 acc[4][4]) {
  const int tid  = threadIdx.x;
  const int lane = tid & 63;
  const int l15  = lane & 15, quad = lane >> 4;
  const int wv   = tid >> 6;
  const int wm   = (wv >> 1) * 64, wn = (wv & 1) * 64;
  const int s0   = wv * 2;
  const int srow = lane >> 2;
  const int scol = (lane & 3) << 3;
  for (int k0 = 0; k0 < 1024; k0 += 32) {
    __syncthreads();
#pragma unroll
    for (int ss = 0; ss < 2; ss++) {
      const int s   = s0 + ss;
      const int row = s * 16 + srow;
      const __bf16* ga = A  + (size_t)(bm + row) * 1024 + k0 + scol;
      const __bf16* gb = Bt + (size_t)(bn + row) * 1024 + k0 + scol;
      __builtin_amdgcn_global_load_lds((const AS1 void*)ga,
                                       (AS3 void*)(At + s * 512), 16, 0, 0);
      __builtin_amdgcn_global_load_lds((const AS1 void*)gb,
                                       (AS3 void*)(Bl + s * 512), 16, 0, 0);
    }
    __syncthreads();
    bf16x8 af[4], bfr[4];
#pragma unroll
    for (int mt = 0; mt < 4; mt++)
      af[mt] = *(const bf16x8*)(At + (wm + mt * 16 + l15) * 32 + quad * 8);
#pragma unroll
    for (int nt = 0; nt < 4; nt++)
      bfr[nt] = *(const bf16x8*)(Bl + (wn + nt * 16 + l15) * 32 + quad * 8);
#pragma unroll
    for (int mt = 0; mt < 4; mt++)
#pragma unroll
      for (int nt = 0; nt < 4; nt++)
        acc[mt][nt] = __builtin_amdgcn_mfma_f32_16x16x32_bf16(
            af[mt], bfr[nt], acc[mt][nt], 0, 0, 0);
  }
}

// ---------------- QKV projection (Q pre-scaled by 1/8; V stored transposed) ----------------
__global__ __launch_bounds__(256) void k_gemm_qkv(const __bf16* __restrict__ xbf,
    const __bf16* __restrict__ wt_all, __bf16* __restrict__ qws,
    __bf16* __restrict__ kws, __bf16* __restrict__ vtws) {
  __shared__ __bf16 At[128 * 32];
  __shared__ __bf16 Bl[128 * 32];
  const int which = blockIdx.z;
  const __bf16* wt = wt_all + (size_t)which * DMODEL * DMODEL;
  const int bm = blockIdx.y * 128, bn = blockIdx.x * 128;
  f32x4 acc[4][4];
  const f32x4 z = {0.f, 0.f, 0.f, 0.f};
#pragma unroll
  for (int mt = 0; mt < 4; mt++)
#pragma unroll
    for (int nt = 0; nt < 4; nt++) acc[mt][nt] = z;
  gemm_mainloop(xbf, wt, bm, bn, At, Bl, acc);
  const int lane = threadIdx.x & 63;
  const int l15 = lane & 15, quad = lane >> 4;
  const int wv = threadIdx.x >> 6;
  const int wm = (wv >> 1) * 64, wn = (wv & 1) * 64;
#pragma unroll
  for (int mt = 0; mt < 4; mt++)
#pragma unroll
    for (int nt = 0; nt < 4; nt++)
#pragma unroll
      for (int r = 0; r < 4; r++) {
        int m = bm + wm + mt * 16 + quad * 4 + r;
        int n = bn + wn + nt * 16 + l15;
        int b = m >> 11, t = m & 2047;
        int h = n >> 6,  d = n & 63;
        int bh = b * 16 + h;
        float av = acc[mt][nt][r];
        if (which == 0)      qws[((size_t)bh * TSEQ + t) * HD + d] = (__bf16)(av * 0.125f);
        else if (which == 1) kws[((size_t)bh * TSEQ + t) * HD + d] = (__bf16)av;
        else                 vtws[((size_t)bh * HD + d) * VSTRIDE + t] = (__bf16)av;
      }
}

// ---------------- flash attention (R6 structure + XCD swizzle + plds stride 72) ----------------
// 1D grid 512: bh = id & 31, qb0 = id >> 5. Round-robin dispatch puts all 16 blocks
// of a bh on XCD bh%8 -> 4 bh/XCD = 2MB K+V, L2-resident re-reads.
__global__ __launch_bounds__(256) void k_attn(const __bf16* __restrict__ qws,
    const __bf16* __restrict__ kws, const __bf16* __restrict__ vtws,
    __bf16* __restrict__ ctx) {
  const int bh  = blockIdx.x & 31;
  const int qb0 = blockIdx.x >> 5, qb1 = 31 - qb0;
  const int tid = threadIdx.x;
  const int lane = tid & 63, wv = tid >> 6;
  const int l15 = lane & 15, quad = lane >> 4;
  const __bf16* qp = qws  + (size_t)bh * TSEQ * HD;
  const __bf16* kp = kws  + (size_t)bh * TSEQ * HD;
  const __bf16* vp = vtws + (size_t)bh * HD * VSTRIDE;
  const int b = bh >> 4, h = bh & 15;

  __shared__ __bf16 kbuf[2][64 * LSTR];
  __shared__ __bf16 vbuf[2][64 * LSTR];
  __shared__ __bf16 plds[4][16 * LSTR];

  const f32x4 z = {0.f, 0.f, 0.f, 0.f};
  const int sr = tid >> 3, sc = (tid & 7) * 8;

  const int qr0a = qb0 * 64 + wv * 16;
  const int qr0b = qb1 * 64 + wv * 16;
  bf16x8 aq0[2], aq1[2];
#pragma unroll
  for (int kb = 0; kb < 2; kb++) {
    aq0[kb] = *(const bf16x8*)(qp + (size_t)(qr0a + l15) * HD + kb * 32 + quad * 8);
    aq1[kb] = *(const bf16x8*)(qp + (size_t)(qr0b + l15) * HD + kb * 32 + quad * 8);
  }

  bf16x8 kreg[2], vreg[2];
  kreg[0] = *(const bf16x8*)(kp + (size_t)sr * HD + sc);
  kreg[1] = *(const bf16x8*)(kp + (size_t)(sr + 32) * HD + sc);
  vreg[0] = *(const bf16x8*)(vp + (size_t)sr * VSTRIDE + sc);
  vreg[1] = *(const bf16x8*)(vp + (size_t)(sr + 32) * VSTRIDE + sc);
  *(bf16x8*)(kbuf[0] + sr * LSTR + sc)        = kreg[0];
  *(bf16x8*)(kbuf[0] + (sr + 32) * LSTR + sc) = kreg[1];
  *(bf16x8*)(vbuf[0] + sr * LSTR + sc)        = vreg[0];
  *(bf16x8*)(vbuf[0] + (sr + 32) * LSTR + sc) = vreg[1];
  __syncthreads();

  float lpart[4] = {0.f, 0.f, 0.f, 0.f};
  f32x4 acc[4];
#pragma unroll
  for (int dt = 0; dt < 4; dt++) acc[dt] = z;

  for (int s = 0; s < 33; s++) {
    const int cur = s & 1;
    const bool h0 = (s <= qb0);
    const bool masked = (s == qb0) || (s == 32);

    if (s + 1 < 33) {
      const int ktn = (s + 1 <= qb0) ? (s + 1) * 64 : (s - qb0) * 64;
      kreg[0] = *(const bf16x8*)(kp + (size_t)(ktn + sr) * HD + sc);
      kreg[1] = *(const bf16x8*)(kp + (size_t)(ktn + sr + 32) * HD + sc);
      vreg[0] = *(const bf16x8*)(vp + (size_t)sr * VSTRIDE + ktn + sc);
      vreg[1] = *(const bf16x8*)(vp + (size_t)(sr + 32) * VSTRIDE + ktn + sc);
    }

    const __bf16* kb_ = kbuf[cur];
    const __bf16* vb_ = vbuf[cur];
    f32x4 sarr[4];
#pragma unroll
    for (int nt = 0; nt < 4; nt++) sarr[nt] = z;
#pragma unroll
    for (int nt = 0; nt < 4; nt++)
#pragma unroll
      for (int kb = 0; kb < 2; kb++) {
        bf16x8 bk = *(const bf16x8*)(kb_ + (nt * 16 + l15) * LSTR + kb * 32 + quad * 8);
        bf16x8 a  = h0 ? aq0[kb] : aq1[kb];
        sarr[nt] = __builtin_amdgcn_mfma_f32_16x16x32_bf16(a, bk, sarr[nt], 0, 0, 0);
      }
    if (masked) {
#pragma unroll
      for (int r = 0; r < 4; r++) {
        const int qloc = wv * 16 + quad * 4 + r;
#pragma unroll
        for (int nt = 0; nt < 4; nt++) {
          int kloc = nt * 16 + l15;
          float p = (kloc <= qloc) ? __expf(sarr[nt][r]) : 0.f;
          lpart[r] += p;
          plds[wv][(quad * 4 + r) * LSTR + nt * 16 + l15] = (__bf16)p;
        }
      }
    } else {
#pragma unroll
      for (int r = 0; r < 4; r++)
#pragma unroll
        for (int nt = 0; nt < 4; nt++) {
          float p = __expf(sarr[nt][r]);
          lpart[r] += p;
          plds[wv][(quad * 4 + r) * LSTR + nt * 16 + l15] = (__bf16)p;
        }
    }
#pragma unroll
    for (int kb = 0; kb < 2; kb++) {
      bf16x8 ap = *(const bf16x8*)(&plds[wv][l15 * LSTR + kb * 32 + quad * 8]);
#pragma unroll
      for (int dt = 0; dt < 4; dt++) {
        bf16x8 bvv = *(const bf16x8*)(vb_ + (dt * 16 + l15) * LSTR + kb * 32 + quad * 8);
        acc[dt] = __builtin_amdgcn_mfma_f32_16x16x32_bf16(ap, bvv, acc[dt], 0, 0, 0);
      }
    }

    if (s + 1 < 33) {
      const int nxt = cur ^ 1;
      *(bf16x8*)(kbuf[nxt] + sr * LSTR + sc)        = kreg[0];
      *(bf16x8*)(kbuf[nxt] + (sr + 32) * LSTR + sc) = kreg[1];
      *(bf16x8*)(vbuf[nxt] + sr * LSTR + sc)        = vreg[0];
      *(bf16x8*)(vbuf[nxt] + (sr + 32) * LSTR + sc) = vreg[1];
    }
    __syncthreads();

    if (masked) {
      const int qr0 = h0 ? qr0a : qr0b;
#pragma unroll
      for (int r = 0; r < 4; r++) {
        float l = lpart[r];
        l += __shfl_xor(l, 1, 64);
        l += __shfl_xor(l, 2, 64);
        l += __shfl_xor(l, 4, 64);
        l += __shfl_xor(l, 8, 64);
        float linv = 1.f / l;
        const int qrow = qr0 + quad * 4 + r;
#pragma unroll
        for (int dt = 0; dt < 4; dt++)
          ctx[((size_t)(b * TSEQ + qrow)) * DMODEL + h * 64 + dt * 16 + l15] =
              (__bf16)(acc[dt][r] * linv);
        lpart[r] = 0.f;
      }
#pragma unroll
      for (int dt = 0; dt < 4; dt++) acc[dt] = z;
    }
  }
}

// ---------------- output projection + bias (fp32 out) ----------------
__global__ __launch_bounds__(256) void k_gemm_out(const __bf16* __restrict__ ctx,
    const __bf16* __restrict__ wot, const float* __restrict__ bo,
    float* __restrict__ out) {
  __shared__ __bf16 At[128 * 32];
  __shared__ __bf16 Bl[128 * 32];
  const int bm = blockIdx.y * 128, bn = blockIdx.x * 128;
  f32x4 acc[4][4];
  const f32x4 z = {0.f, 0.f, 0.f, 0.f};
#pragma unroll
  for (int mt = 0; mt < 4; mt++)
#pragma unroll
    for (int nt = 0; nt < 4; nt++) acc[mt][nt] = z;
  gemm_mainloop(ctx, wot, bm, bn, At, Bl, acc);
  const int lane = threadIdx.x & 63;
  const int l15 = lane & 15, quad = lane >> 4;
  const int wv = threadIdx.x >> 6;
  const int wm = (wv >> 1) * 64, wn = (wv & 1) * 64;
#pragma unroll
  for (int mt = 0; mt < 4; mt++)
#pragma unroll
    for (int nt = 0; nt < 4; nt++)
#pragma unroll
      for (int r = 0; r < 4; r++) {
        int m = bm + wm + mt * 16 + quad * 4 + r;
        int n = bn + wn + nt * 16 + l15;
        out[(size_t)m * DMODEL + n] = acc[mt][nt][r] + bo[n];
      }
}

extern "C" void kernel_launch(void* const* d_in, const int* in_sizes, int n_in,
                              void* d_out, int out_size, void* d_ws, size_t ws_size,
                              hipStream_t stream) {
  const float* x  = (const float*)d_in[0];
  const float* Wq = (const float*)d_in[1];
  const float* Wk = (const float*)d_in[2];
  const float* Wv = (const float*)d_in[3];
  const float* Wo = (const float*)d_in[4];
  const float* bo = (const float*)d_in[5];
  float* out = (float*)d_out;

  __bf16* xbf  = (__bf16*)d_ws;                       // 4096*1024
  __bf16* wt   = xbf  + (size_t)4096 * 1024;          // 4 * 1024*1024
  __bf16* qws  = wt   + (size_t)4 * 1024 * 1024;      // [32][2048][64]
  __bf16* kws  = qws  + (size_t)32 * 2048 * 64;
  __bf16* vtws = kws  + (size_t)32 * 2048 * 64;       // [32][64][VSTRIDE]
  __bf16* ctx  = xbf;                                 // aliases xbf (dead after QKV)

  k_prep<<<8192, 256, 0, stream>>>(x, Wq, Wk, Wv, Wo, xbf, wt);
  k_gemm_qkv<<<dim3(8, 32, 3), 256, 0, stream>>>(xbf, wt, qws, kws, vtws);
  k_attn<<<512, 256, 0, stream>>>(qws, kws, vtws, ctx);
  k_gemm_out<<<dim3(8, 32), 256, 0, stream>>>(ctx, wt + (size_t)3 * 1024 * 1024, bo, out);
}